// Round 4
// baseline (1186.553 us; speedup 1.0000x reference)
//
#include <hip/hip_runtime.h>

#define T_ 4
#define B_ 64
#define L_ 200
#define H_ 256
#define NH_ 2
#define DH_ 128

typedef short short8_t __attribute__((ext_vector_type(8)));
typedef float f32x4 __attribute__((ext_vector_type(4)));

// 8 spike bytes ({0,1}) -> 8 bf16 ({0,1.0}) packed as short8.
__device__ __forceinline__ short8_t unpack_bf16(uint2 v) {
  union { short8_t s; unsigned u[4]; } r;
  r.u[0] = __builtin_amdgcn_perm(0u, v.x, 0x0C010C00u) * 0x3F80u;
  r.u[1] = __builtin_amdgcn_perm(0u, v.x, 0x0C030C02u) * 0x3F80u;
  r.u[2] = __builtin_amdgcn_perm(0u, v.y, 0x0C010C00u) * 0x3F80u;
  r.u[3] = __builtin_amdgcn_perm(0u, v.y, 0x0C030C02u) * 0x3F80u;
  return r.s;
}

// wT64[mat][k][j] = (double)w_mat[j][k]   (4 matrices: qw,kw,vw,pw)
__global__ void transpose_w(const float* __restrict__ qw, const float* __restrict__ kw,
                            const float* __restrict__ vw, const float* __restrict__ pw,
                            double* __restrict__ wT64) {
  int idx = blockIdx.x * 256 + threadIdx.x;   // 0..262143
  int mat = idx >> 16;
  int k = (idx >> 8) & 255;
  int j = idx & 255;
  const float* src = (mat == 0) ? qw : (mat == 1) ? kw : (mat == 2) ? vw : pw;
  wT64[idx] = (double)src[(j << 8) + k];
}

// Fused Linear(no bias) + LayerNorm + LIF(v_th=1), f64 values identical to R1.
// 32-row tile (8 (b,l) pairs x 4 t) staged as f32 (cvt->f64 is exact).
// 256 thr = 64 col-lanes x 4 row-groups; thread = 4 cols (c,c+64,c+128,c+192) x 8 rows.
// LN is wave-local (wave rg owns rows rg*8..rg*8+7 across all 256 cols).
__global__ __launch_bounds__(256)
void branch_kernel(const float* __restrict__ x, const double* __restrict__ wT,
                   const float* __restrict__ lnw, const float* __restrict__ lnb,
                   unsigned char* __restrict__ spk) {
  __shared__ float shx[32 * 256];   // 32 KB
  const int tid = threadIdx.x;
  const int c = tid & 63, rg = tid >> 6;
  const int p0 = blockIdx.x * 8;

  // stage 32 rows of x (coalesced float4)
  for (int i = tid; i < 2048; i += 256) {
    int r = i >> 6, c4 = i & 63;
    int p = r >> 2, t = r & 3;
    int pi = p0 + p;
    int b = pi / L_, l = pi % L_;
    float4 v = ((const float4*)(x + (((size_t)t * B_ + b) * L_ + l) * H_))[c4];
    *(float4*)&shx[r * 256 + c4 * 4] = v;
  }
  __syncthreads();

  // GEMM: rows rg*8..rg*8+7, cols c+64*cc, k ascending (f64)
  double acc[8][4];
#pragma unroll
  for (int i = 0; i < 8; i++)
#pragma unroll
    for (int cc = 0; cc < 4; cc++) acc[i][cc] = 0.0;

#pragma unroll 2
  for (int k = 0; k < 256; k += 2) {
    double w0[4], w1[4];
#pragma unroll
    for (int cc = 0; cc < 4; cc++) {
      w0[cc] = wT[k * 256 + c + 64 * cc];
      w1[cc] = wT[(k + 1) * 256 + c + 64 * cc];
    }
#pragma unroll
    for (int i = 0; i < 8; i++) {
      float2 xv = *(const float2*)&shx[(rg * 8 + i) * 256 + k];
      double x0 = (double)xv.x, x1 = (double)xv.y;
#pragma unroll
      for (int cc = 0; cc < 4; cc++) {
        acc[i][cc] += x0 * w0[cc];
        acc[i][cc] += x1 * w1[cc];
      }
    }
  }

  // LayerNorm stats, wave-local
  double m_[8], rs_[8];
#pragma unroll
  for (int i = 0; i < 8; i++) {
    double s = acc[i][0] + acc[i][1] + acc[i][2] + acc[i][3];
#pragma unroll
    for (int o = 32; o > 0; o >>= 1) s += __shfl_xor(s, o, 64);
    m_[i] = s * (1.0 / 256.0);
    double d0 = acc[i][0] - m_[i], d1 = acc[i][1] - m_[i];
    double d2 = acc[i][2] - m_[i], d3 = acc[i][3] - m_[i];
    double ss = d0 * d0 + d1 * d1 + d2 * d2 + d3 * d3;
#pragma unroll
    for (int o = 32; o > 0; o >>= 1) ss += __shfl_xor(ss, o, 64);
    rs_[i] = 1.0 / sqrt(ss * (1.0 / 256.0) + 1e-5);
  }

  // LIF over t + spike store
#pragma unroll
  for (int cc = 0; cc < 4; cc++) {
    int col = c + 64 * cc;
    int head = col >> 7, d = col & 127;
    double lw = (double)lnw[col], lb = (double)lnb[col];
#pragma unroll
    for (int pl = 0; pl < 2; pl++) {
      int pi = p0 + rg * 2 + pl;
      int b = pi / L_, l = pi % L_;
      double v = 0.0;
#pragma unroll
      for (int t = 0; t < 4; t++) {
        int i = pl * 4 + t;
        double yn = (acc[i][cc] - m_[i]) * rs_[i] * lw + lb;
        v = (v + yn) * 0.5;
        bool f = (v >= 1.0);
        spk[((((size_t)t * B_ + b) * NH_ + head) * L_ + l) * DH_ + d] = f ? (unsigned char)1 : (unsigned char)0;
        if (f) v = 0.0;
      }
    }
  }
}

// V spikes [slab][m<200][d] u8 -> Vt [slab][d][m<224] u8, zero-padded m>=200.
__global__ __launch_bounds__(256)
void vt_prep(const unsigned char* __restrict__ Vs, unsigned char* __restrict__ Vt) {
  const int slab = blockIdx.x;            // 512
  const int w = threadIdx.x >> 6, lane = threadIdx.x & 63;
  const unsigned char* src = Vs + (size_t)slab * (L_ * DH_);
  unsigned char* dst = Vt + (size_t)slab * (DH_ * 224);
  for (int d = w; d < DH_; d += 4) {
    for (int mb = 0; mb < 4; mb++) {
      int m = mb * 64 + lane;
      unsigned char v = 0;
      if (m < L_) v = src[(size_t)m * DH_ + d];
      if (m < 224) dst[(size_t)d * 224 + m] = v;
    }
  }
}

// MFMA attention + attn-LIF(v_th=0.5). Exact (spikes {0,1}, dots <=128, sums <=25600).
__global__ __launch_bounds__(256)
void attn_mfma(const unsigned char* __restrict__ Qs, const unsigned char* __restrict__ Ks,
               const unsigned char* __restrict__ Vt, unsigned char* __restrict__ S2) {
  __shared__ unsigned short sS[32 * 232];
  const int tid = threadIdx.x;
  const int w = tid >> 6, lane = tid & 63;
  const int quad = lane >> 4, ln = lane & 15;
  const int bid = blockIdx.x;
  const int lt = bid % 7;
  const int head = (bid / 7) & 1;
  const int b = bid / 14;
  const int l0 = lt * 32;

  for (int i = tid; i < 32 * 232; i += 256) sS[i] = 0;

  float vmem[2][2][4];
#pragma unroll
  for (int di = 0; di < 2; di++)
#pragma unroll
    for (int ls = 0; ls < 2; ls++)
#pragma unroll
      for (int r = 0; r < 4; r++) vmem[di][ls][r] = 0.f;

  __syncthreads();

  for (int t = 0; t < T_; t++) {
    const int slab = (t * B_ + b) * NH_ + head;
    const unsigned char* qb = Qs + (size_t)slab * (L_ * DH_) + (size_t)l0 * DH_;
    const unsigned char* kb = Ks + (size_t)slab * (L_ * DH_);

    short8_t af[2][4];
#pragma unroll
    for (int ls = 0; ls < 2; ls++)
#pragma unroll
      for (int ks = 0; ks < 4; ks++)
        af[ls][ks] = unpack_bf16(*(const uint2*)(qb + (size_t)(ls * 16 + ln) * DH_ + ks * 32 + quad * 8));

#pragma unroll
    for (int i = 0; i < 4; i++) {
      int nt = w + 4 * i;
      if (nt < 13) {
        short8_t bf[4];
#pragma unroll
        for (int ks = 0; ks < 4; ks++)
          bf[ks] = unpack_bf16(*(const uint2*)(kb + (size_t)(nt * 16 + ln) * DH_ + ks * 32 + quad * 8));
#pragma unroll
        for (int ls = 0; ls < 2; ls++) {
          f32x4 acc = {0.f, 0.f, 0.f, 0.f};
#pragma unroll
          for (int ks = 0; ks < 4; ks++)
            acc = __builtin_amdgcn_mfma_f32_16x16x32_bf16(af[ls][ks], bf[ks], acc, 0, 0, 0);
#pragma unroll
          for (int r = 0; r < 4; r++)
            sS[(ls * 16 + quad * 4 + r) * 232 + nt * 16 + ln] =
                (unsigned short)(__float_as_uint(acc[r]) >> 16);
        }
      }
    }
    __syncthreads();

    const unsigned char* vb = Vt + (size_t)slab * (DH_ * 224);
    f32x4 a2[2][2];
#pragma unroll
    for (int di = 0; di < 2; di++)
#pragma unroll
      for (int ls = 0; ls < 2; ls++) { f32x4 z = {0.f, 0.f, 0.f, 0.f}; a2[di][ls] = z; }

#pragma unroll
    for (int ks = 0; ks < 7; ks++) {
      short8_t s0 = *(const short8_t*)&sS[(0 * 16 + ln) * 232 + ks * 32 + quad * 8];
      short8_t s1 = *(const short8_t*)&sS[(1 * 16 + ln) * 232 + ks * 32 + quad * 8];
#pragma unroll
      for (int di = 0; di < 2; di++) {
        int dt = w + 4 * di;
        short8_t bv = unpack_bf16(*(const uint2*)(vb + (size_t)(dt * 16 + ln) * 224 + ks * 32 + quad * 8));
        a2[di][0] = __builtin_amdgcn_mfma_f32_16x16x32_bf16(s0, bv, a2[di][0], 0, 0, 0);
        a2[di][1] = __builtin_amdgcn_mfma_f32_16x16x32_bf16(s1, bv, a2[di][1], 0, 0, 0);
      }
    }

#pragma unroll
    for (int di = 0; di < 2; di++)
#pragma unroll
      for (int ls = 0; ls < 2; ls++)
#pragma unroll
        for (int r = 0; r < 4; r++) {
          float y = a2[di][ls][r] * 0.125f;
          float v = (vmem[di][ls][r] + y) * 0.5f;
          bool f = (v >= 0.5f);
          int l = l0 + ls * 16 + quad * 4 + r;
          if (l < L_)
            S2[(((size_t)t * B_ + b) * L_ + l) * H_ + head * DH_ + (w + 4 * di) * 16 + ln] =
                f ? (unsigned char)1 : (unsigned char)0;
          vmem[di][ls][r] = f ? 0.f : v;
        }
    __syncthreads();
  }
}

// Fused proj Linear(+bias) + LayerNorm + LIF(v_th=1) -> {0,1} floats.
// Same structure as branch_kernel; spikes staged bytes->f32 via dword loads.
__global__ __launch_bounds__(256)
void proj_kernel(const unsigned char* __restrict__ s2, const double* __restrict__ pwT,
                 const float* __restrict__ pb, const float* __restrict__ lnw,
                 const float* __restrict__ lnb, float* __restrict__ out) {
  __shared__ float shx[32 * 256];
  const int tid = threadIdx.x;
  const int c = tid & 63, rg = tid >> 6;
  const int p0 = blockIdx.x * 8;

  for (int i = tid; i < 2048; i += 256) {
    int r = i >> 6, c4 = i & 63;
    int p = r >> 2, t = r & 3;
    int pi = p0 + p;
    int b = pi / L_, l = pi % L_;
    unsigned u = ((const unsigned*)(s2 + (((size_t)t * B_ + b) * L_ + l) * H_))[c4];
    float4 v;
    v.x = (float)(u & 255u);
    v.y = (float)((u >> 8) & 255u);
    v.z = (float)((u >> 16) & 255u);
    v.w = (float)(u >> 24);
    *(float4*)&shx[r * 256 + c4 * 4] = v;
  }
  __syncthreads();

  double acc[8][4];
#pragma unroll
  for (int cc = 0; cc < 4; cc++) {
    double bj = (double)pb[c + 64 * cc];
#pragma unroll
    for (int i = 0; i < 8; i++) acc[i][cc] = bj;
  }

#pragma unroll 2
  for (int k = 0; k < 256; k += 2) {
    double w0[4], w1[4];
#pragma unroll
    for (int cc = 0; cc < 4; cc++) {
      w0[cc] = pwT[k * 256 + c + 64 * cc];
      w1[cc] = pwT[(k + 1) * 256 + c + 64 * cc];
    }
#pragma unroll
    for (int i = 0; i < 8; i++) {
      float2 xv = *(const float2*)&shx[(rg * 8 + i) * 256 + k];
      double x0 = (double)xv.x, x1 = (double)xv.y;
#pragma unroll
      for (int cc = 0; cc < 4; cc++) {
        acc[i][cc] += x0 * w0[cc];
        acc[i][cc] += x1 * w1[cc];
      }
    }
  }

  double m_[8], rs_[8];
#pragma unroll
  for (int i = 0; i < 8; i++) {
    double s = acc[i][0] + acc[i][1] + acc[i][2] + acc[i][3];
#pragma unroll
    for (int o = 32; o > 0; o >>= 1) s += __shfl_xor(s, o, 64);
    m_[i] = s * (1.0 / 256.0);
    double d0 = acc[i][0] - m_[i], d1 = acc[i][1] - m_[i];
    double d2 = acc[i][2] - m_[i], d3 = acc[i][3] - m_[i];
    double ss = d0 * d0 + d1 * d1 + d2 * d2 + d3 * d3;
#pragma unroll
    for (int o = 32; o > 0; o >>= 1) ss += __shfl_xor(ss, o, 64);
    rs_[i] = 1.0 / sqrt(ss * (1.0 / 256.0) + 1e-5);
  }

#pragma unroll
  for (int cc = 0; cc < 4; cc++) {
    int col = c + 64 * cc;
    double lw = (double)lnw[col], lb = (double)lnb[col];
#pragma unroll
    for (int pl = 0; pl < 2; pl++) {
      int pi = p0 + rg * 2 + pl;
      int b = pi / L_, l = pi % L_;
      double v = 0.0;
#pragma unroll
      for (int t = 0; t < 4; t++) {
        int i = pl * 4 + t;
        double yn = (acc[i][cc] - m_[i]) * rs_[i] * lw + lb;
        v = (v + yn) * 0.5;
        bool f = (v >= 1.0);
        out[(((size_t)t * B_ + b) * L_ + l) * H_ + col] = f ? 1.0f : 0.0f;
        if (f) v = 0.0;
      }
    }
  }
}

extern "C" void kernel_launch(void* const* d_in, const int* in_sizes, int n_in,
                              void* d_out, int out_size, void* d_ws, size_t ws_size,
                              hipStream_t stream) {
  (void)in_sizes; (void)n_in; (void)out_size; (void)ws_size;
  const float* x    = (const float*)d_in[0];
  const float* qw   = (const float*)d_in[1];
  const float* qlnw = (const float*)d_in[2];
  const float* qlnb = (const float*)d_in[3];
  const float* kw   = (const float*)d_in[4];
  const float* klnw = (const float*)d_in[5];
  const float* klnb = (const float*)d_in[6];
  const float* vw   = (const float*)d_in[7];
  const float* vlnw = (const float*)d_in[8];
  const float* vlnb = (const float*)d_in[9];
  const float* pw   = (const float*)d_in[10];
  const float* pb   = (const float*)d_in[11];
  const float* plnw = (const float*)d_in[12];
  const float* plnb = (const float*)d_in[13];

  char* ws = (char*)d_ws;
  const size_t SPK = (size_t)T_ * B_ * NH_ * L_ * DH_;     // 13,107,200 bytes
  double* wT64 = (double*)ws;                              // 2 MB
  unsigned char* Qsp = (unsigned char*)(ws + (1 << 21));
  unsigned char* Ksp = Qsp + SPK;
  unsigned char* Vsp = Ksp + SPK;
  unsigned char* S2  = Vsp;                                // alias: Vsp dead after vt_prep
  unsigned char* Vt  = Vsp + SPK;                          // total ~55.5 MB

  hipLaunchKernelGGL(transpose_w, dim3(1024), dim3(256), 0, stream, qw, kw, vw, pw, wT64);
  hipLaunchKernelGGL(branch_kernel, dim3(1600), dim3(256), 0, stream, x, wT64,          qlnw, qlnb, Qsp);
  hipLaunchKernelGGL(branch_kernel, dim3(1600), dim3(256), 0, stream, x, wT64 + 65536,  klnw, klnb, Ksp);
  hipLaunchKernelGGL(branch_kernel, dim3(1600), dim3(256), 0, stream, x, wT64 + 131072, vlnw, vlnb, Vsp);
  hipLaunchKernelGGL(vt_prep, dim3(512), dim3(256), 0, stream, Vsp, Vt);
  hipLaunchKernelGGL(attn_mfma, dim3(896), dim3(256), 0, stream, Qsp, Ksp, Vt, S2);
  hipLaunchKernelGGL(proj_kernel, dim3(1600), dim3(256), 0, stream, S2, wT64 + 196608, pb, plnw, plnb, (float*)d_out);
}

// Round 5
// 881.911 us; speedup vs baseline: 1.3454x; 1.3454x over previous
//
#include <hip/hip_runtime.h>

#define T_ 4
#define B_ 64
#define L_ 200
#define H_ 256
#define NH_ 2
#define DH_ 128

typedef short short8_t __attribute__((ext_vector_type(8)));
typedef float f32x4 __attribute__((ext_vector_type(4)));

// 8 spike bytes ({0,1}) -> 8 bf16 ({0,1.0}) packed as short8.
__device__ __forceinline__ short8_t unpack_bf16(uint2 v) {
  union { short8_t s; unsigned u[4]; } r;
  r.u[0] = __builtin_amdgcn_perm(0u, v.x, 0x0C010C00u) * 0x3F80u;
  r.u[1] = __builtin_amdgcn_perm(0u, v.x, 0x0C030C02u) * 0x3F80u;
  r.u[2] = __builtin_amdgcn_perm(0u, v.y, 0x0C010C00u) * 0x3F80u;
  r.u[3] = __builtin_amdgcn_perm(0u, v.y, 0x0C030C02u) * 0x3F80u;
  return r.s;
}

// Pack weights for the GEMM kernels' access pattern:
// wP[((mat*128 + kp)*64 + c)*8 + kk*4 + cc] = w_mat[c + 64*cc][2*kp + kk]
// so thread-lane c reads its 8 per-k-pair weights as two contiguous float4.
__global__ void pack_w(const float* __restrict__ qw, const float* __restrict__ kw,
                       const float* __restrict__ vw, const float* __restrict__ pw,
                       float* __restrict__ wP) {
  int idx = blockIdx.x * 256 + threadIdx.x;   // 0..262143
  int mat = idx >> 16;
  int r = idx & 65535;
  int kp = r >> 9;
  int c  = (r >> 3) & 63;
  int kk = (r >> 2) & 1;
  int cc = r & 3;
  const float* src = (mat == 0) ? qw : (mat == 1) ? kw : (mat == 2) ? vw : pw;
  wP[idx] = src[(c + 64 * cc) * 256 + (2 * kp + kk)];
}

// Fused Linear(no bias) + LayerNorm + LIF(v_th=1), f64 values identical to R1.
// 32-row tile (8 (b,l) pairs x 4 t) staged as f64 in LDS (cvt once at stage).
// 256 thr = 64 col-lanes x 4 row-group waves; thread = 4 cols x 8 rows.
// k-loop: 8 broadcast ds_read_b128 (x f64) + 2 global float4 (packed w) + 32 f64 FMA.
// No barriers in the k-loop. LN wave-local. 64KB LDS -> 2 blocks/CU.
__global__ __launch_bounds__(256, 2)
void branch_kernel(const float* __restrict__ x, const float* __restrict__ wP,
                   const float* __restrict__ lnw, const float* __restrict__ lnb,
                   unsigned char* __restrict__ spk) {
  __shared__ double shx[32 * 256];   // 64 KB
  const int tid = threadIdx.x;
  const int c = tid & 63, rg = tid >> 6;
  const int p0 = blockIdx.x * 8;

  // stage 32 rows of x as f64 (coalesced float4 reads, exact cvt)
  for (int i = tid; i < 2048; i += 256) {
    int r = i >> 6, c4 = i & 63;
    int p = r >> 2, t = r & 3;
    int pi = p0 + p;
    int b = pi / L_, l = pi % L_;
    float4 v = ((const float4*)(x + (((size_t)t * B_ + b) * L_ + l) * H_))[c4];
    double* dst = &shx[r * 256 + c4 * 4];
    dst[0] = (double)v.x; dst[1] = (double)v.y; dst[2] = (double)v.z; dst[3] = (double)v.w;
  }
  __syncthreads();

  const float4* wp4 = (const float4*)wP;   // packed: idx (kp*64+c)*2 and +1

  double acc[8][4];
#pragma unroll
  for (int i = 0; i < 8; i++)
#pragma unroll
    for (int cc = 0; cc < 4; cc++) acc[i][cc] = 0.0;

#pragma unroll 2
  for (int kp = 0; kp < 128; kp++) {
    float4 f0 = wp4[(kp * 64 + c) * 2];
    float4 f1 = wp4[(kp * 64 + c) * 2 + 1];
    double w0[4], w1[4];
    w0[0] = (double)f0.x; w0[1] = (double)f0.y; w0[2] = (double)f0.z; w0[3] = (double)f0.w;
    w1[0] = (double)f1.x; w1[1] = (double)f1.y; w1[2] = (double)f1.z; w1[3] = (double)f1.w;
#pragma unroll
    for (int i = 0; i < 8; i++) {
      double2 xv = *(const double2*)&shx[(rg * 8 + i) * 256 + 2 * kp];  // wave-broadcast
#pragma unroll
      for (int cc = 0; cc < 4; cc++) {
        acc[i][cc] += xv.x * w0[cc];
        acc[i][cc] += xv.y * w1[cc];
      }
    }
  }

  // LayerNorm stats, wave-local (wave rg owns rows rg*8..rg*8+7, lanes span 256 cols)
  double m_[8], rs_[8];
#pragma unroll
  for (int i = 0; i < 8; i++) {
    double s = acc[i][0] + acc[i][1] + acc[i][2] + acc[i][3];
#pragma unroll
    for (int o = 32; o > 0; o >>= 1) s += __shfl_xor(s, o, 64);
    m_[i] = s * (1.0 / 256.0);
    double d0 = acc[i][0] - m_[i], d1 = acc[i][1] - m_[i];
    double d2 = acc[i][2] - m_[i], d3 = acc[i][3] - m_[i];
    double ss = d0 * d0 + d1 * d1 + d2 * d2 + d3 * d3;
#pragma unroll
    for (int o = 32; o > 0; o >>= 1) ss += __shfl_xor(ss, o, 64);
    rs_[i] = 1.0 / sqrt(ss * (1.0 / 256.0) + 1e-5);
  }

  // LIF over t + spike store in attention layout
#pragma unroll
  for (int cc = 0; cc < 4; cc++) {
    int col = c + 64 * cc;
    int head = col >> 7, d = col & 127;
    double lw = (double)lnw[col], lb = (double)lnb[col];
#pragma unroll
    for (int pl = 0; pl < 2; pl++) {
      int pi = p0 + rg * 2 + pl;
      int b = pi / L_, l = pi % L_;
      double v = 0.0;
#pragma unroll
      for (int t = 0; t < 4; t++) {
        int i = pl * 4 + t;
        double yn = (acc[i][cc] - m_[i]) * rs_[i] * lw + lb;
        v = (v + yn) * 0.5;
        bool f = (v >= 1.0);
        spk[((((size_t)t * B_ + b) * NH_ + head) * L_ + l) * DH_ + d] = f ? (unsigned char)1 : (unsigned char)0;
        if (f) v = 0.0;
      }
    }
  }
}

// V spikes [slab][m<200][d] u8 -> Vt [slab][d][m<224] u8, zero-padded m>=200.
__global__ __launch_bounds__(256)
void vt_prep(const unsigned char* __restrict__ Vs, unsigned char* __restrict__ Vt) {
  const int slab = blockIdx.x;            // 512
  const int w = threadIdx.x >> 6, lane = threadIdx.x & 63;
  const unsigned char* src = Vs + (size_t)slab * (L_ * DH_);
  unsigned char* dst = Vt + (size_t)slab * (DH_ * 224);
  for (int d = w; d < DH_; d += 4) {
    for (int mb = 0; mb < 4; mb++) {
      int m = mb * 64 + lane;
      unsigned char v = 0;
      if (m < L_) v = src[(size_t)m * DH_ + d];
      if (m < 224) dst[(size_t)d * 224 + m] = v;
    }
  }
}

// MFMA attention + attn-LIF(v_th=0.5). Exact (spikes {0,1}, dots <=128, sums <=25600).
__global__ __launch_bounds__(256)
void attn_mfma(const unsigned char* __restrict__ Qs, const unsigned char* __restrict__ Ks,
               const unsigned char* __restrict__ Vt, unsigned char* __restrict__ S2) {
  __shared__ unsigned short sS[32 * 232];
  const int tid = threadIdx.x;
  const int w = tid >> 6, lane = tid & 63;
  const int quad = lane >> 4, ln = lane & 15;
  const int bid = blockIdx.x;
  const int lt = bid % 7;
  const int head = (bid / 7) & 1;
  const int b = bid / 14;
  const int l0 = lt * 32;

  for (int i = tid; i < 32 * 232; i += 256) sS[i] = 0;

  float vmem[2][2][4];
#pragma unroll
  for (int di = 0; di < 2; di++)
#pragma unroll
    for (int ls = 0; ls < 2; ls++)
#pragma unroll
      for (int r = 0; r < 4; r++) vmem[di][ls][r] = 0.f;

  __syncthreads();

  for (int t = 0; t < T_; t++) {
    const int slab = (t * B_ + b) * NH_ + head;
    const unsigned char* qb = Qs + (size_t)slab * (L_ * DH_) + (size_t)l0 * DH_;
    const unsigned char* kb = Ks + (size_t)slab * (L_ * DH_);

    short8_t af[2][4];
#pragma unroll
    for (int ls = 0; ls < 2; ls++)
#pragma unroll
      for (int ks = 0; ks < 4; ks++)
        af[ls][ks] = unpack_bf16(*(const uint2*)(qb + (size_t)(ls * 16 + ln) * DH_ + ks * 32 + quad * 8));

#pragma unroll
    for (int i = 0; i < 4; i++) {
      int nt = w + 4 * i;
      if (nt < 13) {
        short8_t bf[4];
#pragma unroll
        for (int ks = 0; ks < 4; ks++)
          bf[ks] = unpack_bf16(*(const uint2*)(kb + (size_t)(nt * 16 + ln) * DH_ + ks * 32 + quad * 8));
#pragma unroll
        for (int ls = 0; ls < 2; ls++) {
          f32x4 acc = {0.f, 0.f, 0.f, 0.f};
#pragma unroll
          for (int ks = 0; ks < 4; ks++)
            acc = __builtin_amdgcn_mfma_f32_16x16x32_bf16(af[ls][ks], bf[ks], acc, 0, 0, 0);
#pragma unroll
          for (int r = 0; r < 4; r++)
            sS[(ls * 16 + quad * 4 + r) * 232 + nt * 16 + ln] =
                (unsigned short)(__float_as_uint(acc[r]) >> 16);
        }
      }
    }
    __syncthreads();

    const unsigned char* vb = Vt + (size_t)slab * (DH_ * 224);
    f32x4 a2[2][2];
#pragma unroll
    for (int di = 0; di < 2; di++)
#pragma unroll
      for (int ls = 0; ls < 2; ls++) { f32x4 z = {0.f, 0.f, 0.f, 0.f}; a2[di][ls] = z; }

#pragma unroll
    for (int ks = 0; ks < 7; ks++) {
      short8_t s0 = *(const short8_t*)&sS[(0 * 16 + ln) * 232 + ks * 32 + quad * 8];
      short8_t s1 = *(const short8_t*)&sS[(1 * 16 + ln) * 232 + ks * 32 + quad * 8];
#pragma unroll
      for (int di = 0; di < 2; di++) {
        int dt = w + 4 * di;
        short8_t bv = unpack_bf16(*(const uint2*)(vb + (size_t)(dt * 16 + ln) * 224 + ks * 32 + quad * 8));
        a2[di][0] = __builtin_amdgcn_mfma_f32_16x16x32_bf16(s0, bv, a2[di][0], 0, 0, 0);
        a2[di][1] = __builtin_amdgcn_mfma_f32_16x16x32_bf16(s1, bv, a2[di][1], 0, 0, 0);
      }
    }

#pragma unroll
    for (int di = 0; di < 2; di++)
#pragma unroll
      for (int ls = 0; ls < 2; ls++)
#pragma unroll
        for (int r = 0; r < 4; r++) {
          float y = a2[di][ls][r] * 0.125f;
          float v = (vmem[di][ls][r] + y) * 0.5f;
          bool f = (v >= 0.5f);
          int l = l0 + ls * 16 + quad * 4 + r;
          if (l < L_)
            S2[(((size_t)t * B_ + b) * L_ + l) * H_ + head * DH_ + (w + 4 * di) * 16 + ln] =
                f ? (unsigned char)1 : (unsigned char)0;
          vmem[di][ls][r] = f ? 0.f : v;
        }
    __syncthreads();
  }
}

// Fused proj Linear(+bias) + LayerNorm + LIF(v_th=1) -> {0,1} floats.
// Same structure as branch_kernel; spike bytes staged to f64 LDS once.
__global__ __launch_bounds__(256, 2)
void proj_kernel(const unsigned char* __restrict__ s2, const float* __restrict__ wPp,
                 const float* __restrict__ pb, const float* __restrict__ lnw,
                 const float* __restrict__ lnb, float* __restrict__ out) {
  __shared__ double shx[32 * 256];
  const int tid = threadIdx.x;
  const int c = tid & 63, rg = tid >> 6;
  const int p0 = blockIdx.x * 8;

  for (int i = tid; i < 2048; i += 256) {
    int r = i >> 6, c4 = i & 63;
    int p = r >> 2, t = r & 3;
    int pi = p0 + p;
    int b = pi / L_, l = pi % L_;
    unsigned u = ((const unsigned*)(s2 + (((size_t)t * B_ + b) * L_ + l) * H_))[c4];
    double* dst = &shx[r * 256 + c4 * 4];
    dst[0] = (double)(u & 255u);
    dst[1] = (double)((u >> 8) & 255u);
    dst[2] = (double)((u >> 16) & 255u);
    dst[3] = (double)(u >> 24);
  }
  __syncthreads();

  const float4* wp4 = (const float4*)wPp;

  double acc[8][4];
#pragma unroll
  for (int cc = 0; cc < 4; cc++) {
    double bj = (double)pb[c + 64 * cc];
#pragma unroll
    for (int i = 0; i < 8; i++) acc[i][cc] = bj;
  }

#pragma unroll 2
  for (int kp = 0; kp < 128; kp++) {
    float4 f0 = wp4[(kp * 64 + c) * 2];
    float4 f1 = wp4[(kp * 64 + c) * 2 + 1];
    double w0[4], w1[4];
    w0[0] = (double)f0.x; w0[1] = (double)f0.y; w0[2] = (double)f0.z; w0[3] = (double)f0.w;
    w1[0] = (double)f1.x; w1[1] = (double)f1.y; w1[2] = (double)f1.z; w1[3] = (double)f1.w;
#pragma unroll
    for (int i = 0; i < 8; i++) {
      double2 xv = *(const double2*)&shx[(rg * 8 + i) * 256 + 2 * kp];
#pragma unroll
      for (int cc = 0; cc < 4; cc++) {
        acc[i][cc] += xv.x * w0[cc];
        acc[i][cc] += xv.y * w1[cc];
      }
    }
  }

  double m_[8], rs_[8];
#pragma unroll
  for (int i = 0; i < 8; i++) {
    double s = acc[i][0] + acc[i][1] + acc[i][2] + acc[i][3];
#pragma unroll
    for (int o = 32; o > 0; o >>= 1) s += __shfl_xor(s, o, 64);
    m_[i] = s * (1.0 / 256.0);
    double d0 = acc[i][0] - m_[i], d1 = acc[i][1] - m_[i];
    double d2 = acc[i][2] - m_[i], d3 = acc[i][3] - m_[i];
    double ss = d0 * d0 + d1 * d1 + d2 * d2 + d3 * d3;
#pragma unroll
    for (int o = 32; o > 0; o >>= 1) ss += __shfl_xor(ss, o, 64);
    rs_[i] = 1.0 / sqrt(ss * (1.0 / 256.0) + 1e-5);
  }

#pragma unroll
  for (int cc = 0; cc < 4; cc++) {
    int col = c + 64 * cc;
    double lw = (double)lnw[col], lb = (double)lnb[col];
#pragma unroll
    for (int pl = 0; pl < 2; pl++) {
      int pi = p0 + rg * 2 + pl;
      int b = pi / L_, l = pi % L_;
      double v = 0.0;
#pragma unroll
      for (int t = 0; t < 4; t++) {
        int i = pl * 4 + t;
        double yn = (acc[i][cc] - m_[i]) * rs_[i] * lw + lb;
        v = (v + yn) * 0.5;
        bool f = (v >= 1.0);
        out[(((size_t)t * B_ + b) * L_ + l) * H_ + col] = f ? 1.0f : 0.0f;
        if (f) v = 0.0;
      }
    }
  }
}

extern "C" void kernel_launch(void* const* d_in, const int* in_sizes, int n_in,
                              void* d_out, int out_size, void* d_ws, size_t ws_size,
                              hipStream_t stream) {
  (void)in_sizes; (void)n_in; (void)out_size; (void)ws_size;
  const float* x    = (const float*)d_in[0];
  const float* qw   = (const float*)d_in[1];
  const float* qlnw = (const float*)d_in[2];
  const float* qlnb = (const float*)d_in[3];
  const float* kw   = (const float*)d_in[4];
  const float* klnw = (const float*)d_in[5];
  const float* klnb = (const float*)d_in[6];
  const float* vw   = (const float*)d_in[7];
  const float* vlnw = (const float*)d_in[8];
  const float* vlnb = (const float*)d_in[9];
  const float* pw   = (const float*)d_in[10];
  const float* pb   = (const float*)d_in[11];
  const float* plnw = (const float*)d_in[12];
  const float* plnb = (const float*)d_in[13];

  char* ws = (char*)d_ws;
  const size_t SPK = (size_t)T_ * B_ * NH_ * L_ * DH_;     // 13,107,200 bytes
  float* wP = (float*)ws;                                  // 1 MB packed weights
  unsigned char* Qsp = (unsigned char*)(ws + (1 << 20));
  unsigned char* Ksp = Qsp + SPK;
  unsigned char* Vsp = Ksp + SPK;
  unsigned char* S2  = Vsp;                                // alias: Vsp dead after vt_prep
  unsigned char* Vt  = Vsp + SPK;                          // total ~53.5 MB

  hipLaunchKernelGGL(pack_w, dim3(1024), dim3(256), 0, stream, qw, kw, vw, pw, wP);
  hipLaunchKernelGGL(branch_kernel, dim3(1600), dim3(256), 0, stream, x, wP,          qlnw, qlnb, Qsp);
  hipLaunchKernelGGL(branch_kernel, dim3(1600), dim3(256), 0, stream, x, wP + 65536,  klnw, klnb, Ksp);
  hipLaunchKernelGGL(branch_kernel, dim3(1600), dim3(256), 0, stream, x, wP + 131072, vlnw, vlnb, Vsp);
  hipLaunchKernelGGL(vt_prep, dim3(512), dim3(256), 0, stream, Vsp, Vt);
  hipLaunchKernelGGL(attn_mfma, dim3(896), dim3(256), 0, stream, Qsp, Ksp, Vt, S2);
  hipLaunchKernelGGL(proj_kernel, dim3(1600), dim3(256), 0, stream, S2, wP + 196608, pb, plnw, plnb, (float*)d_out);
}

// Round 8
// 732.036 us; speedup vs baseline: 1.6209x; 1.2047x over previous
//
#include <hip/hip_runtime.h>

#define T_ 4
#define B_ 64
#define L_ 200
#define H_ 256
#define NH_ 2
#define DH_ 128

typedef short short8_t __attribute__((ext_vector_type(8)));
typedef float f32x4 __attribute__((ext_vector_type(4)));
typedef double f64x4 __attribute__((ext_vector_type(4)));

#define MFMA_F64(a, b, c) __builtin_amdgcn_mfma_f64_16x16x4f64((a), (b), (c), 0, 0, 0)

// 8 spike bytes ({0,1}) -> 8 bf16 ({0,1.0}) packed as short8.
__device__ __forceinline__ short8_t unpack_bf16(uint2 v) {
  union { short8_t s; unsigned u[4]; } r;
  r.u[0] = __builtin_amdgcn_perm(0u, v.x, 0x0C010C00u) * 0x3F80u;
  r.u[1] = __builtin_amdgcn_perm(0u, v.x, 0x0C030C02u) * 0x3F80u;
  r.u[2] = __builtin_amdgcn_perm(0u, v.y, 0x0C010C00u) * 0x3F80u;
  r.u[3] = __builtin_amdgcn_perm(0u, v.y, 0x0C030C02u) * 0x3F80u;
  return r.s;
}

// Pack weights into f64 MFMA B-fragments.
// wB[((mat*16 + nt)*64 + kb)*64 + lane] = (double)w_mat[nt*16 + (lane&15)][kb*4 + (lane>>4)]
// (B[k][n] fragment: lane = n + 16k), so the k-loop B load is one coalesced dwordx2.
__global__ void pack_wB(const float* __restrict__ qw, const float* __restrict__ kw,
                        const float* __restrict__ vw, const float* __restrict__ pw,
                        double* __restrict__ wB) {
  int idx = blockIdx.x * 256 + threadIdx.x;   // 0..262143
  int mat = idx >> 16;
  int r = idx & 65535;
  int nt = r >> 12;
  int kb = (r >> 6) & 63;
  int ln2 = r & 63;
  int n = ln2 & 15, k = ln2 >> 4;
  const float* src = (mat == 0) ? qw : (mat == 1) ? kw : (mat == 2) ? vw : pw;
  wB[idx] = (double)src[(nt * 16 + n) * 256 + kb * 4 + k];
}

// Fused Linear + LayerNorm + LIF via f64 MFMA (16x16x4). f64-accurate -> exact spikes.
// Layout self-discovery: probe MFMAs determine the D row map (two candidate
// hypotheses) and the actual D column per lane; staging is permuted so that in
// both row-map cases lane (q,ln) reg i holds content row 4q+i (pair q, t=i).
template <bool IS_PROJ>
__global__ __launch_bounds__(256, 2)
void gemm_ln_lif(const float* __restrict__ xf, const unsigned char* __restrict__ xs,
                 const double* __restrict__ wB, const float* __restrict__ bias,
                 const float* __restrict__ lnw, const float* __restrict__ lnb,
                 unsigned char* __restrict__ spk, float* __restrict__ out) {
  __shared__ float shx[32 * 260];   // stride 260: <=2-way LDS banks for A reads
  __shared__ double red[32][4];
  const int tid = threadIdx.x;
  const int w = tid >> 6, lane = tid & 63;
  const int q = lane >> 4, ln = lane & 15;
  const int p0 = blockIdx.x * 8;

  // ---- layout probes ----
  f64x4 pz = {0.0, 0.0, 0.0, 0.0};
  f64x4 pr = MFMA_F64((double)ln, 1.0, pz);   // D[m][n] = 4m -> reg i's actual row
  f64x4 pc = MFMA_F64(1.0, (double)ln, pz);   // D[m][n] = 4n -> lane's actual col
  bool hyp1 = (pr[0] == (double)(4 * (4 * q + 0))) && (pr[1] == (double)(4 * (4 * q + 1))) &&
              (pr[2] == (double)(4 * (4 * q + 2))) && (pr[3] == (double)(4 * (4 * q + 3)));
  const int nc = (int)(pc[0] * 0.25);         // actual n within 16-col tile

  // stage 32 rows of input as f32; A-row slot r gets content row (perm within m-tile)
  for (int i = tid; i < 2048; i += 256) {
    int r = i >> 6, c4 = i & 63;
    int mt = r >> 4, a = r & 15;
    int ca = hyp1 ? a : (4 * (a & 3) + (a >> 2));   // involution
    int cr = 16 * mt + ca;
    int p = cr >> 2, t = cr & 3;
    int pi = p0 + p;
    int b = pi / L_, l = pi % L_;
    size_t n = ((size_t)t * B_ + b) * L_ + l;
    float4 v;
    if (IS_PROJ) {
      unsigned u = ((const unsigned*)(xs + n * H_))[c4];
      v.x = (float)(u & 255u); v.y = (float)((u >> 8) & 255u);
      v.z = (float)((u >> 16) & 255u); v.w = (float)(u >> 24);
    } else {
      v = ((const float4*)(xf + n * H_))[c4];
    }
    *(float4*)&shx[r * 260 + c4 * 4] = v;
  }
  __syncthreads();

  // accumulators: acc[mt][j] = D tile (m-tile mt, n-tile w*4+j); init bias (proj) or 0
  f64x4 acc[2][4];
#pragma unroll
  for (int j = 0; j < 4; j++) {
    double c0 = IS_PROJ ? (double)bias[(w * 4 + j) * 16 + nc] : 0.0;
    f64x4 z = {c0, c0, c0, c0};
    acc[0][j] = z; acc[1][j] = z;
  }

  const double* wb = wB + (size_t)(w * 4) * 4096;   // n-tile stride 64*64
  for (int kb = 0; kb < 64; kb++) {
    double a0 = (double)shx[ln * 260 + kb * 4 + q];          // A[m=ln][k=q], m-tile 0
    double a1 = (double)shx[(ln + 16) * 260 + kb * 4 + q];   // m-tile 1
#pragma unroll
    for (int j = 0; j < 4; j++) {
      double bv = wb[(size_t)j * 4096 + kb * 64 + lane];
      acc[0][j] = MFMA_F64(a0, bv, acc[0][j]);
      acc[1][j] = MFMA_F64(a1, bv, acc[1][j]);
    }
  }

  // In BOTH hypotheses, lane (q,ln) reg i now holds CONTENT row 4q+i of its m-tile
  // (pair q, t=i), at column (w*4+j)*16 + nc.

  // LayerNorm pass 1: row sums
#pragma unroll
  for (int mt = 0; mt < 2; mt++)
#pragma unroll
    for (int i = 0; i < 4; i++) {
      double s = acc[mt][0][i] + acc[mt][1][i] + acc[mt][2][i] + acc[mt][3][i];
#pragma unroll
      for (int o = 1; o < 16; o <<= 1) s += __shfl_xor(s, o, 64);
      if (ln == 0) red[16 * mt + 4 * q + i][w] = s;
    }
  __syncthreads();
  double m_[2][4];
#pragma unroll
  for (int mt = 0; mt < 2; mt++)
#pragma unroll
    for (int i = 0; i < 4; i++) {
      int r = 16 * mt + 4 * q + i;
      m_[mt][i] = (red[r][0] + red[r][1] + red[r][2] + red[r][3]) * (1.0 / 256.0);
    }
  __syncthreads();
  // pass 2: variance
#pragma unroll
  for (int mt = 0; mt < 2; mt++)
#pragma unroll
    for (int i = 0; i < 4; i++) {
      double d0 = acc[mt][0][i] - m_[mt][i], d1 = acc[mt][1][i] - m_[mt][i];
      double d2 = acc[mt][2][i] - m_[mt][i], d3 = acc[mt][3][i] - m_[mt][i];
      double ss = d0 * d0 + d1 * d1 + d2 * d2 + d3 * d3;
#pragma unroll
      for (int o = 1; o < 16; o <<= 1) ss += __shfl_xor(ss, o, 64);
      if (ln == 0) red[16 * mt + 4 * q + i][w] = ss;
    }
  __syncthreads();
  double rs_[2][4];
#pragma unroll
  for (int mt = 0; mt < 2; mt++)
#pragma unroll
    for (int i = 0; i < 4; i++) {
      int r = 16 * mt + 4 * q + i;
      double var = (red[r][0] + red[r][1] + red[r][2] + red[r][3]) * (1.0 / 256.0);
      rs_[mt][i] = 1.0 / sqrt(var + 1e-5);
    }

  // LIF over t (in-register; lane's rows are all 4 t of pairs q and q+4)
#pragma unroll
  for (int mt = 0; mt < 2; mt++) {
    int pi = p0 + 4 * mt + q;
    int b = pi / L_, l = pi % L_;
#pragma unroll
    for (int j = 0; j < 4; j++) {
      int col = (w * 4 + j) * 16 + nc;
      double lw = (double)lnw[col], lb = (double)lnb[col];
      double v = 0.0;
#pragma unroll
      for (int t = 0; t < 4; t++) {
        double yn = (acc[mt][j][t] - m_[mt][t]) * rs_[mt][t] * lw + lb;
        v = (v + yn) * 0.5;
        bool f = (v >= 1.0);
        size_t n = ((size_t)t * B_ + b) * L_ + l;
        if (IS_PROJ) {
          out[n * H_ + col] = f ? 1.0f : 0.0f;
        } else {
          int head = col >> 7, d = col & 127;
          spk[((((size_t)t * B_ + b) * NH_ + head) * L_ + l) * DH_ + d] = f ? (unsigned char)1 : (unsigned char)0;
        }
        if (f) v = 0.0;
      }
    }
  }
}

// V spikes [slab][m<200][d] u8 -> Vt [slab][d][m<224] u8, zero-padded m>=200.
__global__ __launch_bounds__(256)
void vt_prep(const unsigned char* __restrict__ Vs, unsigned char* __restrict__ Vt) {
  const int slab = blockIdx.x;            // 512
  const int w = threadIdx.x >> 6, lane = threadIdx.x & 63;
  const unsigned char* src = Vs + (size_t)slab * (L_ * DH_);
  unsigned char* dst = Vt + (size_t)slab * (DH_ * 224);
  for (int d = w; d < DH_; d += 4) {
    for (int mb = 0; mb < 4; mb++) {
      int m = mb * 64 + lane;
      unsigned char v = 0;
      if (m < L_) v = src[(size_t)m * DH_ + d];
      if (m < 224) dst[(size_t)d * 224 + m] = v;
    }
  }
}

// MFMA attention + attn-LIF(v_th=0.5). Exact (spikes {0,1}, dots <=128, sums <=25600).
__global__ __launch_bounds__(256)
void attn_mfma(const unsigned char* __restrict__ Qs, const unsigned char* __restrict__ Ks,
               const unsigned char* __restrict__ Vt, unsigned char* __restrict__ S2) {
  __shared__ unsigned short sS[32 * 232];
  const int tid = threadIdx.x;
  const int w = tid >> 6, lane = tid & 63;
  const int quad = lane >> 4, ln = lane & 15;
  const int bid = blockIdx.x;
  const int lt = bid % 7;
  const int head = (bid / 7) & 1;
  const int b = bid / 14;
  const int l0 = lt * 32;

  for (int i = tid; i < 32 * 232; i += 256) sS[i] = 0;

  float vmem[2][2][4];
#pragma unroll
  for (int di = 0; di < 2; di++)
#pragma unroll
    for (int ls = 0; ls < 2; ls++)
#pragma unroll
      for (int r = 0; r < 4; r++) vmem[di][ls][r] = 0.f;

  __syncthreads();

  for (int t = 0; t < T_; t++) {
    const int slab = (t * B_ + b) * NH_ + head;
    const unsigned char* qb = Qs + (size_t)slab * (L_ * DH_) + (size_t)l0 * DH_;
    const unsigned char* kb = Ks + (size_t)slab * (L_ * DH_);

    short8_t af[2][4];
#pragma unroll
    for (int ls = 0; ls < 2; ls++)
#pragma unroll
      for (int ks = 0; ks < 4; ks++)
        af[ls][ks] = unpack_bf16(*(const uint2*)(qb + (size_t)(ls * 16 + ln) * DH_ + ks * 32 + quad * 8));

#pragma unroll
    for (int i = 0; i < 4; i++) {
      int nt = w + 4 * i;
      if (nt < 13) {
        short8_t bf[4];
#pragma unroll
        for (int ks = 0; ks < 4; ks++)
          bf[ks] = unpack_bf16(*(const uint2*)(kb + (size_t)(nt * 16 + ln) * DH_ + ks * 32 + quad * 8));
#pragma unroll
        for (int ls = 0; ls < 2; ls++) {
          f32x4 acc = {0.f, 0.f, 0.f, 0.f};
#pragma unroll
          for (int ks = 0; ks < 4; ks++)
            acc = __builtin_amdgcn_mfma_f32_16x16x32_bf16(af[ls][ks], bf[ks], acc, 0, 0, 0);
#pragma unroll
          for (int r = 0; r < 4; r++)
            sS[(ls * 16 + quad * 4 + r) * 232 + nt * 16 + ln] =
                (unsigned short)(__float_as_uint(acc[r]) >> 16);
        }
      }
    }
    __syncthreads();

    const unsigned char* vb = Vt + (size_t)slab * (DH_ * 224);
    f32x4 a2[2][2];
#pragma unroll
    for (int di = 0; di < 2; di++)
#pragma unroll
      for (int ls = 0; ls < 2; ls++) { f32x4 z = {0.f, 0.f, 0.f, 0.f}; a2[di][ls] = z; }

#pragma unroll
    for (int ks = 0; ks < 7; ks++) {
      short8_t s0 = *(const short8_t*)&sS[(0 * 16 + ln) * 232 + ks * 32 + quad * 8];
      short8_t s1 = *(const short8_t*)&sS[(1 * 16 + ln) * 232 + ks * 32 + quad * 8];
#pragma unroll
      for (int di = 0; di < 2; di++) {
        int dt = w + 4 * di;
        short8_t bv = unpack_bf16(*(const uint2*)(vb + (size_t)(dt * 16 + ln) * 224 + ks * 32 + quad * 8));
        a2[di][0] = __builtin_amdgcn_mfma_f32_16x16x32_bf16(s0, bv, a2[di][0], 0, 0, 0);
        a2[di][1] = __builtin_amdgcn_mfma_f32_16x16x32_bf16(s1, bv, a2[di][1], 0, 0, 0);
      }
    }

#pragma unroll
    for (int di = 0; di < 2; di++)
#pragma unroll
      for (int ls = 0; ls < 2; ls++)
#pragma unroll
        for (int r = 0; r < 4; r++) {
          float y = a2[di][ls][r] * 0.125f;
          float v = (vmem[di][ls][r] + y) * 0.5f;
          bool f = (v >= 0.5f);
          int l = l0 + ls * 16 + quad * 4 + r;
          if (l < L_)
            S2[(((size_t)t * B_ + b) * L_ + l) * H_ + head * DH_ + (w + 4 * di) * 16 + ln] =
                f ? (unsigned char)1 : (unsigned char)0;
          vmem[di][ls][r] = f ? 0.f : v;
        }
    __syncthreads();
  }
}

extern "C" void kernel_launch(void* const* d_in, const int* in_sizes, int n_in,
                              void* d_out, int out_size, void* d_ws, size_t ws_size,
                              hipStream_t stream) {
  (void)in_sizes; (void)n_in; (void)out_size; (void)ws_size;
  const float* x    = (const float*)d_in[0];
  const float* qw   = (const float*)d_in[1];
  const float* qlnw = (const float*)d_in[2];
  const float* qlnb = (const float*)d_in[3];
  const float* kw   = (const float*)d_in[4];
  const float* klnw = (const float*)d_in[5];
  const float* klnb = (const float*)d_in[6];
  const float* vw   = (const float*)d_in[7];
  const float* vlnw = (const float*)d_in[8];
  const float* vlnb = (const float*)d_in[9];
  const float* pw   = (const float*)d_in[10];
  const float* pb   = (const float*)d_in[11];
  const float* plnw = (const float*)d_in[12];
  const float* plnb = (const float*)d_in[13];

  char* ws = (char*)d_ws;
  const size_t SPK = (size_t)T_ * B_ * NH_ * L_ * DH_;     // 13,107,200 bytes
  double* wB = (double*)ws;                                // 2 MB packed f64 B-fragments
  unsigned char* Qsp = (unsigned char*)(ws + (1 << 21));
  unsigned char* Ksp = Qsp + SPK;
  unsigned char* Vsp = Ksp + SPK;
  unsigned char* S2  = Vsp;                                // alias: Vsp dead after vt_prep
  unsigned char* Vt  = Vsp + SPK;                          // total ~56 MB

  hipLaunchKernelGGL(pack_wB, dim3(1024), dim3(256), 0, stream, qw, kw, vw, pw, wB);
  hipLaunchKernelGGL((gemm_ln_lif<false>), dim3(1600), dim3(256), 0, stream,
                     x, (const unsigned char*)nullptr, wB,          (const float*)nullptr, qlnw, qlnb, Qsp, (float*)nullptr);
  hipLaunchKernelGGL((gemm_ln_lif<false>), dim3(1600), dim3(256), 0, stream,
                     x, (const unsigned char*)nullptr, wB + 65536,  (const float*)nullptr, klnw, klnb, Ksp, (float*)nullptr);
  hipLaunchKernelGGL((gemm_ln_lif<false>), dim3(1600), dim3(256), 0, stream,
                     x, (const unsigned char*)nullptr, wB + 131072, (const float*)nullptr, vlnw, vlnb, Vsp, (float*)nullptr);
  hipLaunchKernelGGL(vt_prep, dim3(512), dim3(256), 0, stream, Vsp, Vt);
  hipLaunchKernelGGL(attn_mfma, dim3(896), dim3(256), 0, stream, Qsp, Ksp, Vt, S2);
  hipLaunchKernelGGL((gemm_ln_lif<true>), dim3(1600), dim3(256), 0, stream,
                     (const float*)nullptr, S2, wB + 196608, pb, plnw, plnb, (unsigned char*)nullptr, (float*)d_out);
}

// Round 10
// 574.578 us; speedup vs baseline: 2.0651x; 1.2740x over previous
//
#include <hip/hip_runtime.h>

#define T_ 4
#define B_ 64
#define L_ 200
#define H_ 256
#define NH_ 2
#define DH_ 128
#define LCAP 12800

typedef short short8_t __attribute__((ext_vector_type(8)));
typedef float f32x4 __attribute__((ext_vector_type(4)));

#define MFMA_BF16(a, b, c) __builtin_amdgcn_mfma_f32_16x16x32_bf16((a), (b), (c), 0, 0, 0)

__device__ __forceinline__ unsigned short bf16rn(float f) {
  unsigned u = __float_as_uint(f);
  return (unsigned short)((u + 0x7FFFu + ((u >> 16) & 1u)) >> 16);
}
__device__ __forceinline__ float bf16tof(unsigned short h) {
  return __uint_as_float(((unsigned)h) << 16);
}

// 8 spike bytes ({0,1}) -> 8 bf16 ({0,1.0}) packed as short8.
__device__ __forceinline__ short8_t unpack_bf16(uint2 v) {
  union { short8_t s; unsigned u[4]; } r;
  r.u[0] = __builtin_amdgcn_perm(0u, v.x, 0x0C010C00u) * 0x3F80u;
  r.u[1] = __builtin_amdgcn_perm(0u, v.x, 0x0C030C02u) * 0x3F80u;
  r.u[2] = __builtin_amdgcn_perm(0u, v.y, 0x0C010C00u) * 0x3F80u;
  r.u[3] = __builtin_amdgcn_perm(0u, v.y, 0x0C030C02u) * 0x3F80u;
  return r.s;
}

// Pack: wT[mat][k][j] = w[j][k] (f32, for exact fixup), and bf16 3-split B-fragments:
// wf[(((mat*3+s)*16+nt)*8+kc)*512 + lane*8 + j] = split_s(w[nt*16+(lane&15)][kc*32+(lane>>4)*8+j])
// fid count = 4*3*16*8*64 = 98304 (NOT 196608 = per-matrix SHORT stride — R9's overflow bug).
__global__ void pack_w(const float* __restrict__ qw, const float* __restrict__ kw,
                       const float* __restrict__ vw, const float* __restrict__ pw,
                       short* __restrict__ wf, float* __restrict__ wT) {
  int id = blockIdx.x * 256 + threadIdx.x;
  if (id < 262144) {
    int mat = id >> 16, k = (id >> 8) & 255, j = id & 255;
    const float* src = (mat == 0) ? qw : (mat == 1) ? kw : (mat == 2) ? vw : pw;
    wT[id] = src[j * 256 + k];
  }
  int fid = id - 262144;
  if (fid >= 0 && fid < 98304) {
    int lane = fid & 63, kc = (fid >> 6) & 7, nt = (fid >> 9) & 15, ms = fid >> 13;
    int mat = ms / 3, s = ms - mat * 3;
    const float* src = (mat == 0) ? qw : (mat == 1) ? kw : (mat == 2) ? vw : pw;
    int n = nt * 16 + (lane & 15), q = lane >> 4;
    for (int j = 0; j < 8; j++) {
      float v = src[n * 256 + kc * 32 + q * 8 + j];
      unsigned short h1 = bf16rn(v);
      float r1 = v - bf16tof(h1);
      unsigned short h2 = bf16rn(r1);
      float r2 = r1 - bf16tof(h2);
      unsigned short h3 = bf16rn(r2);
      wf[fid * 8 + j] = (short)((s == 0) ? h1 : (s == 1) ? h2 : h3);
    }
  }
}

__global__ void zero_cnt(int* __restrict__ cnt) {
  if (threadIdx.x < 4) cnt[threadIdx.x] = 0;
}

// Approx Linear(+bias) + LN + LIF via split-bf16 MFMA, with margin flagging.
// Block: 32 rows (8 pairs x 4 t) x 256 cols, 4 waves. Wave w: n-tiles w*4..w*4+3.
// D layout (verified): col=lane&15, row=(lane>>4)*4+reg -> lane q holds all 4 t of
// pairs q (mt0), q+4 (mt1) => LN/LIF in registers. Flagged pairs -> list for f64 fixup.
template <bool IS_PROJ>
__global__ __launch_bounds__(256, 2)
void gemm_approx(const float* __restrict__ xf, const unsigned char* __restrict__ xs,
                 const short* __restrict__ wfm, const float* __restrict__ bias,
                 const float* __restrict__ lnw, const float* __restrict__ lnb,
                 unsigned char* __restrict__ spk, float* __restrict__ out,
                 int* __restrict__ cnt, int* __restrict__ list) {
  constexpr int NS = IS_PROJ ? 1 : 3;
  __shared__ short sa[NS * 8192];   // [s][mt][kc][slot^(kc&7)][8]
  __shared__ double red[32][4];
  __shared__ int pf[8];
  const int tid = threadIdx.x;
  const int w = tid >> 6, lane = tid & 63;
  const int q = lane >> 4, ln = lane & 15;
  const int p0 = blockIdx.x * 8;

  if (tid < 8) pf[tid] = 0;

  // stage: each thread handles 4 chunks of 8 consecutive k in one row
  for (int it = 0; it < 4; it++) {
    int cid = tid + 256 * it;      // 0..1023
    int r = cid >> 5, ck = cid & 31;
    int k0 = ck * 8, kc = ck >> 2, cq = ck & 3;
    int mt = r >> 4, m = r & 15;
    int p = r >> 2, t = r & 3;
    int pi = p0 + p;
    int b = pi / L_, l = pi % L_;
    size_t nrow = ((size_t)t * B_ + b) * L_ + l;
    int base = ((mt * 8 + kc) * 512) + (((cq * 16 + m) ^ (kc & 7)) * 8);
    if (IS_PROJ) {
      uint2 u = *(const uint2*)(xs + nrow * H_ + k0);
      *(short8_t*)&sa[base] = unpack_bf16(u);
    } else {
      float4 v0 = *(const float4*)(xf + nrow * H_ + k0);
      float4 v1 = *(const float4*)(xf + nrow * H_ + k0 + 4);
      float f[8] = {v0.x, v0.y, v0.z, v0.w, v1.x, v1.y, v1.z, v1.w};
      union { short8_t v; short s[8]; } H1, H2, H3;
#pragma unroll
      for (int e = 0; e < 8; e++) {
        unsigned short h1 = bf16rn(f[e]);
        float r1 = f[e] - bf16tof(h1);
        unsigned short h2 = bf16rn(r1);
        float r2 = r1 - bf16tof(h2);
        unsigned short h3 = bf16rn(r2);
        H1.s[e] = (short)h1; H2.s[e] = (short)h2; H3.s[e] = (short)h3;
      }
      *(short8_t*)&sa[base] = H1.v;
      *(short8_t*)&sa[base + 8192] = H2.v;
      *(short8_t*)&sa[base + 16384] = H3.v;
    }
  }
  __syncthreads();

  f32x4 hi[2][4], mid[2][4], lo[2][4];
#pragma unroll
  for (int mt = 0; mt < 2; mt++)
#pragma unroll
    for (int jj = 0; jj < 4; jj++) {
      f32x4 z = {0.f, 0.f, 0.f, 0.f};
      hi[mt][jj] = z; mid[mt][jj] = z; lo[mt][jj] = z;
    }

  for (int kc = 0; kc < 8; kc++) {
    int ap = (lane ^ (kc & 7)) * 8;
    short8_t a0[2], a1[2], a2[2];
    a0[0] = *(const short8_t*)&sa[(0 * 8 + kc) * 512 + ap];
    a0[1] = *(const short8_t*)&sa[(1 * 8 + kc) * 512 + ap];
    if (!IS_PROJ) {
      a1[0] = *(const short8_t*)&sa[8192 + (0 * 8 + kc) * 512 + ap];
      a1[1] = *(const short8_t*)&sa[8192 + (1 * 8 + kc) * 512 + ap];
      a2[0] = *(const short8_t*)&sa[16384 + (0 * 8 + kc) * 512 + ap];
      a2[1] = *(const short8_t*)&sa[16384 + (1 * 8 + kc) * 512 + ap];
    }
#pragma unroll
    for (int jj = 0; jj < 4; jj++) {
      int nt = w * 4 + jj;
      const short* bp = wfm + ((size_t)(nt * 8 + kc)) * 512 + lane * 8;
      short8_t b0 = *(const short8_t*)bp;
      short8_t b1 = *(const short8_t*)(bp + 65536);
      short8_t b2 = *(const short8_t*)(bp + 131072);
#pragma unroll
      for (int mt = 0; mt < 2; mt++) {
        hi[mt][jj] = MFMA_BF16(a0[mt], b0, hi[mt][jj]);
        if (IS_PROJ) {
          mid[mt][jj] = MFMA_BF16(a0[mt], b1, mid[mt][jj]);
          lo[mt][jj] = MFMA_BF16(a0[mt], b2, lo[mt][jj]);
        } else {
          mid[mt][jj] = MFMA_BF16(a0[mt], b1, mid[mt][jj]);
          mid[mt][jj] = MFMA_BF16(a1[mt], b0, mid[mt][jj]);
          lo[mt][jj] = MFMA_BF16(a0[mt], b2, lo[mt][jj]);
          lo[mt][jj] = MFMA_BF16(a1[mt], b1, lo[mt][jj]);
          lo[mt][jj] = MFMA_BF16(a2[mt], b0, lo[mt][jj]);
        }
      }
    }
  }

  // combine groups in f64
  double y64[2][4][4];
#pragma unroll
  for (int mt = 0; mt < 2; mt++)
#pragma unroll
    for (int jj = 0; jj < 4; jj++) {
      double bj = IS_PROJ ? (double)bias[(w * 4 + jj) * 16 + ln] : 0.0;
#pragma unroll
      for (int i = 0; i < 4; i++)
        y64[mt][jj][i] = (double)hi[mt][jj][i] + (double)mid[mt][jj][i] + (double)lo[mt][jj][i] + bj;
    }

  // LayerNorm stats (row r = mt*16 + 4q + i)
#pragma unroll
  for (int mt = 0; mt < 2; mt++)
#pragma unroll
    for (int i = 0; i < 4; i++) {
      double s = y64[mt][0][i] + y64[mt][1][i] + y64[mt][2][i] + y64[mt][3][i];
#pragma unroll
      for (int o = 1; o < 16; o <<= 1) s += __shfl_xor(s, o, 64);
      if (ln == 0) red[16 * mt + 4 * q + i][w] = s;
    }
  __syncthreads();
  double m_[2][4];
#pragma unroll
  for (int mt = 0; mt < 2; mt++)
#pragma unroll
    for (int i = 0; i < 4; i++) {
      int r = 16 * mt + 4 * q + i;
      m_[mt][i] = (red[r][0] + red[r][1] + red[r][2] + red[r][3]) * (1.0 / 256.0);
    }
  __syncthreads();
#pragma unroll
  for (int mt = 0; mt < 2; mt++)
#pragma unroll
    for (int i = 0; i < 4; i++) {
      double d0 = y64[mt][0][i] - m_[mt][i], d1 = y64[mt][1][i] - m_[mt][i];
      double d2 = y64[mt][2][i] - m_[mt][i], d3 = y64[mt][3][i] - m_[mt][i];
      double ss = d0 * d0 + d1 * d1 + d2 * d2 + d3 * d3;
#pragma unroll
      for (int o = 1; o < 16; o <<= 1) ss += __shfl_xor(ss, o, 64);
      if (ln == 0) red[16 * mt + 4 * q + i][w] = ss;
    }
  __syncthreads();
  double rs_[2][4], tolr[2][4];
#pragma unroll
  for (int mt = 0; mt < 2; mt++)
#pragma unroll
    for (int i = 0; i < 4; i++) {
      int r = 16 * mt + 4 * q + i;
      double var = (red[r][0] + red[r][1] + red[r][2] + red[r][3]) * (1.0 / 256.0);
      rs_[mt][i] = 1.0 / sqrt(var + 1e-5);
      tolr[mt][i] = 1e-4 + 2e-6 * (4.0 + fabs(m_[mt][i]) * rs_[mt][i]);
    }

  // LIF + margin flag
  int fl[2] = {0, 0};
#pragma unroll
  for (int mt = 0; mt < 2; mt++) {
    int pi = p0 + 4 * mt + q;
    int b = pi / L_, l = pi % L_;
#pragma unroll
    for (int jj = 0; jj < 4; jj++) {
      int col = (w * 4 + jj) * 16 + ln;
      double lw = (double)lnw[col], lb = (double)lnb[col];
      double v = 0.0;
#pragma unroll
      for (int t = 0; t < 4; t++) {
        double yn = (y64[mt][jj][t] - m_[mt][t]) * rs_[mt][t] * lw + lb;
        v = (v + yn) * 0.5;
        bool f = (v >= 1.0);
        if (fabs(v - 1.0) < tolr[mt][t]) fl[mt] = 1;
        size_t n = ((size_t)t * B_ + b) * L_ + l;
        if (IS_PROJ) {
          out[n * H_ + col] = f ? 1.0f : 0.0f;
        } else {
          int head = col >> 7, d = col & 127;
          spk[((((size_t)t * B_ + b) * NH_ + head) * L_ + l) * DH_ + d] = f ? (unsigned char)1 : (unsigned char)0;
        }
        if (f) v = 0.0;
      }
    }
  }
#pragma unroll
  for (int o = 1; o < 16; o <<= 1) {
    fl[0] |= __shfl_xor(fl[0], o, 64);
    fl[1] |= __shfl_xor(fl[1], o, 64);
  }
  if (ln == 0) {
    if (fl[0]) atomicOr(&pf[q], 1);
    if (fl[1]) atomicOr(&pf[4 + q], 1);
  }
  __syncthreads();
  if (tid < 8 && pf[tid]) {
    int idx = atomicAdd(cnt, 1);
    if (idx < LCAP) list[idx] = p0 + tid;
  }
}

// Exact f64 recompute of flagged pairs (same math as the R5/R8-passing f64 path).
template <bool IS_PROJ>
__global__ __launch_bounds__(256)
void fixup(const float* __restrict__ xf, const unsigned char* __restrict__ xs,
           const float* __restrict__ wT, const float* __restrict__ bias,
           const float* __restrict__ lnw, const float* __restrict__ lnb,
           unsigned char* __restrict__ spk, float* __restrict__ out,
           const int* __restrict__ cnt, const int* __restrict__ list) {
  __shared__ double rsum[4][4];
  __shared__ double mv[4], rsd[4];
  const int tid = threadIdx.x;
  const int w = tid >> 6;
  int n = *cnt; if (n > LCAP) n = LCAP;
  for (int e = blockIdx.x; e < n; e += gridDim.x) {
    int pi = list[e];
    int b = pi / L_, l = pi % L_;
    int j = tid;
    size_t nrow[4];
#pragma unroll
    for (int t = 0; t < 4; t++) nrow[t] = ((size_t)t * B_ + b) * L_ + l;
    double acc[4];
#pragma unroll
    for (int t = 0; t < 4; t++) acc[t] = IS_PROJ ? (double)bias[j] : 0.0;
    for (int k = 0; k < 256; k++) {
      double wv = (double)wT[k * 256 + j];
#pragma unroll
      for (int t = 0; t < 4; t++) {
        double xv = IS_PROJ ? (double)xs[nrow[t] * H_ + k] : (double)xf[nrow[t] * H_ + k];
        acc[t] += xv * wv;
      }
    }
#pragma unroll
    for (int t = 0; t < 4; t++) {
      double s = acc[t];
#pragma unroll
      for (int o = 1; o < 64; o <<= 1) s += __shfl_xor(s, o, 64);
      if ((tid & 63) == 0) rsum[w][t] = s;
    }
    __syncthreads();
    if (tid < 4) mv[tid] = (rsum[0][tid] + rsum[1][tid] + rsum[2][tid] + rsum[3][tid]) * (1.0 / 256.0);
    __syncthreads();
#pragma unroll
    for (int t = 0; t < 4; t++) {
      double d = acc[t] - mv[t];
      double ss = d * d;
#pragma unroll
      for (int o = 1; o < 64; o <<= 1) ss += __shfl_xor(ss, o, 64);
      if ((tid & 63) == 0) rsum[w][t] = ss;
    }
    __syncthreads();
    if (tid < 4) {
      double var = (rsum[0][tid] + rsum[1][tid] + rsum[2][tid] + rsum[3][tid]) * (1.0 / 256.0);
      rsd[tid] = 1.0 / sqrt(var + 1e-5);
    }
    __syncthreads();
    double lw = (double)lnw[j], lb = (double)lnb[j];
    double v = 0.0;
#pragma unroll
    for (int t = 0; t < 4; t++) {
      double yn = (acc[t] - mv[t]) * rsd[t] * lw + lb;
      v = (v + yn) * 0.5;
      bool f = (v >= 1.0);
      if (IS_PROJ) {
        out[nrow[t] * H_ + j] = f ? 1.0f : 0.0f;
      } else {
        int head = j >> 7, d = j & 127;
        spk[((((size_t)t * B_ + b) * NH_ + head) * L_ + l) * DH_ + d] = f ? (unsigned char)1 : (unsigned char)0;
      }
      if (f) v = 0.0;
    }
    __syncthreads();
  }
}

// V spikes [slab][m<200][d] u8 -> Vt [slab][d][m<224] u8, zero-padded m>=200.
__global__ __launch_bounds__(256)
void vt_prep(const unsigned char* __restrict__ Vs, unsigned char* __restrict__ Vt) {
  const int slab = blockIdx.x;
  const int w = threadIdx.x >> 6, lane = threadIdx.x & 63;
  const unsigned char* src = Vs + (size_t)slab * (L_ * DH_);
  unsigned char* dst = Vt + (size_t)slab * (DH_ * 224);
  for (int d = w; d < DH_; d += 4) {
    for (int mb = 0; mb < 4; mb++) {
      int m = mb * 64 + lane;
      unsigned char v = 0;
      if (m < L_) v = src[(size_t)m * DH_ + d];
      if (m < 224) dst[(size_t)d * 224 + m] = v;
    }
  }
}

// MFMA attention + attn-LIF(v_th=0.5). Exact (spikes {0,1}, dots <=128, sums <=25600).
__global__ __launch_bounds__(256)
void attn_mfma(const unsigned char* __restrict__ Qs, const unsigned char* __restrict__ Ks,
               const unsigned char* __restrict__ Vt, unsigned char* __restrict__ S2) {
  __shared__ unsigned short sS[32 * 232];
  const int tid = threadIdx.x;
  const int w = tid >> 6, lane = tid & 63;
  const int quad = lane >> 4, ln = lane & 15;
  const int bid = blockIdx.x;
  const int lt = bid % 7;
  const int head = (bid / 7) & 1;
  const int b = bid / 14;
  const int l0 = lt * 32;

  for (int i = tid; i < 32 * 232; i += 256) sS[i] = 0;

  float vmem[2][2][4];
#pragma unroll
  for (int di = 0; di < 2; di++)
#pragma unroll
    for (int ls = 0; ls < 2; ls++)
#pragma unroll
      for (int r = 0; r < 4; r++) vmem[di][ls][r] = 0.f;

  __syncthreads();

  for (int t = 0; t < T_; t++) {
    const int slab = (t * B_ + b) * NH_ + head;
    const unsigned char* qb = Qs + (size_t)slab * (L_ * DH_) + (size_t)l0 * DH_;
    const unsigned char* kb = Ks + (size_t)slab * (L_ * DH_);

    short8_t af[2][4];
#pragma unroll
    for (int ls = 0; ls < 2; ls++)
#pragma unroll
      for (int ks = 0; ks < 4; ks++)
        af[ls][ks] = unpack_bf16(*(const uint2*)(qb + (size_t)(ls * 16 + ln) * DH_ + ks * 32 + quad * 8));

#pragma unroll
    for (int i = 0; i < 4; i++) {
      int nt = w + 4 * i;
      if (nt < 13) {
        short8_t bf[4];
#pragma unroll
        for (int ks = 0; ks < 4; ks++)
          bf[ks] = unpack_bf16(*(const uint2*)(kb + (size_t)(nt * 16 + ln) * DH_ + ks * 32 + quad * 8));
#pragma unroll
        for (int ls = 0; ls < 2; ls++) {
          f32x4 acc = {0.f, 0.f, 0.f, 0.f};
#pragma unroll
          for (int ks = 0; ks < 4; ks++)
            acc = MFMA_BF16(af[ls][ks], bf[ks], acc);
#pragma unroll
          for (int r = 0; r < 4; r++)
            sS[(ls * 16 + quad * 4 + r) * 232 + nt * 16 + ln] =
                (unsigned short)(__float_as_uint(acc[r]) >> 16);
        }
      }
    }
    __syncthreads();

    const unsigned char* vb = Vt + (size_t)slab * (DH_ * 224);
    f32x4 a2[2][2];
#pragma unroll
    for (int di = 0; di < 2; di++)
#pragma unroll
      for (int ls = 0; ls < 2; ls++) { f32x4 z = {0.f, 0.f, 0.f, 0.f}; a2[di][ls] = z; }

#pragma unroll
    for (int ks = 0; ks < 7; ks++) {
      short8_t s0 = *(const short8_t*)&sS[(0 * 16 + ln) * 232 + ks * 32 + quad * 8];
      short8_t s1 = *(const short8_t*)&sS[(1 * 16 + ln) * 232 + ks * 32 + quad * 8];
#pragma unroll
      for (int di = 0; di < 2; di++) {
        int dt = w + 4 * di;
        short8_t bv = unpack_bf16(*(const uint2*)(vb + (size_t)(dt * 16 + ln) * 224 + ks * 32 + quad * 8));
        a2[di][0] = MFMA_BF16(s0, bv, a2[di][0]);
        a2[di][1] = MFMA_BF16(s1, bv, a2[di][1]);
      }
    }

#pragma unroll
    for (int di = 0; di < 2; di++)
#pragma unroll
      for (int ls = 0; ls < 2; ls++)
#pragma unroll
        for (int r = 0; r < 4; r++) {
          float y = a2[di][ls][r] * 0.125f;
          float v = (vmem[di][ls][r] + y) * 0.5f;
          bool f = (v >= 0.5f);
          int l = l0 + ls * 16 + quad * 4 + r;
          if (l < L_)
            S2[(((size_t)t * B_ + b) * L_ + l) * H_ + head * DH_ + (w + 4 * di) * 16 + ln] =
                f ? (unsigned char)1 : (unsigned char)0;
          vmem[di][ls][r] = f ? 0.f : v;
        }
    __syncthreads();
  }
}

extern "C" void kernel_launch(void* const* d_in, const int* in_sizes, int n_in,
                              void* d_out, int out_size, void* d_ws, size_t ws_size,
                              hipStream_t stream) {
  (void)in_sizes; (void)n_in; (void)out_size; (void)ws_size;
  const float* x    = (const float*)d_in[0];
  const float* qw   = (const float*)d_in[1];
  const float* qlnw = (const float*)d_in[2];
  const float* qlnb = (const float*)d_in[3];
  const float* kw   = (const float*)d_in[4];
  const float* klnw = (const float*)d_in[5];
  const float* klnb = (const float*)d_in[6];
  const float* vw   = (const float*)d_in[7];
  const float* vlnw = (const float*)d_in[8];
  const float* vlnb = (const float*)d_in[9];
  const float* pw   = (const float*)d_in[10];
  const float* pb   = (const float*)d_in[11];
  const float* plnw = (const float*)d_in[12];
  const float* plnb = (const float*)d_in[13];

  char* ws = (char*)d_ws;
  const size_t SPK = (size_t)T_ * B_ * NH_ * L_ * DH_;     // 13,107,200
  short* wf  = (short*)ws;                                  // 98304*8*2 = 1,572,864 B
  float* wT  = (float*)(ws + 1572864);                      // 1,048,576 B
  int*  cnt  = (int*)(ws + 2621440);                        // 16 B
  int*  list = (int*)(ws + 2621696);                        // 204,800 B
  unsigned char* Qsp = (unsigned char*)(ws + 2826496);
  unsigned char* Ksp = Qsp + SPK;
  unsigned char* Vsp = Ksp + SPK;
  unsigned char* S2  = Vsp;                                 // alias after vt_prep
  unsigned char* Vt  = Vsp + SPK;                           // ~54.2 MiB total

  hipLaunchKernelGGL(pack_w, dim3(1408), dim3(256), 0, stream, qw, kw, vw, pw, wf, wT);
  hipLaunchKernelGGL(zero_cnt, dim3(1), dim3(64), 0, stream, cnt);

  hipLaunchKernelGGL((gemm_approx<false>), dim3(1600), dim3(256), 0, stream,
                     x, (const unsigned char*)nullptr, wf,           (const float*)nullptr, qlnw, qlnb, Qsp, (float*)nullptr, cnt + 0, list + 0 * LCAP);
  hipLaunchKernelGGL((gemm_approx<false>), dim3(1600), dim3(256), 0, stream,
                     x, (const unsigned char*)nullptr, wf + 196608,  (const float*)nullptr, klnw, klnb, Ksp, (float*)nullptr, cnt + 1, list + 1 * LCAP);
  hipLaunchKernelGGL((gemm_approx<false>), dim3(1600), dim3(256), 0, stream,
                     x, (const unsigned char*)nullptr, wf + 393216,  (const float*)nullptr, vlnw, vlnb, Vsp, (float*)nullptr, cnt + 2, list + 2 * LCAP);

  hipLaunchKernelGGL((fixup<false>), dim3(512), dim3(256), 0, stream,
                     x, (const unsigned char*)nullptr, wT,          (const float*)nullptr, qlnw, qlnb, Qsp, (float*)nullptr, cnt + 0, list + 0 * LCAP);
  hipLaunchKernelGGL((fixup<false>), dim3(512), dim3(256), 0, stream,
                     x, (const unsigned char*)nullptr, wT + 65536,  (const float*)nullptr, klnw, klnb, Ksp, (float*)nullptr, cnt + 1, list + 1 * LCAP);
  hipLaunchKernelGGL((fixup<false>), dim3(512), dim3(256), 0, stream,
                     x, (const unsigned char*)nullptr, wT + 131072, (const float*)nullptr, vlnw, vlnb, Vsp, (float*)nullptr, cnt + 2, list + 2 * LCAP);

  hipLaunchKernelGGL(vt_prep, dim3(512), dim3(256), 0, stream, Vsp, Vt);
  hipLaunchKernelGGL(attn_mfma, dim3(896), dim3(256), 0, stream, Qsp, Ksp, Vt, S2);

  hipLaunchKernelGGL((gemm_approx<true>), dim3(1600), dim3(256), 0, stream,
                     (const float*)nullptr, S2, wf + 589824, pb, plnw, plnb, (unsigned char*)nullptr, (float*)d_out, cnt + 3, list + 3 * LCAP);
  hipLaunchKernelGGL((fixup<true>), dim3(512), dim3(256), 0, stream,
                     (const float*)nullptr, S2, wT + 196608, pb, plnw, plnb, (unsigned char*)nullptr, (float*)d_out, cnt + 3, list + 3 * LCAP);
}